// Round 1
// baseline (461.850 us; speedup 1.0000x reference)
//
#include <hip/hip_runtime.h>

// ---------------------------------------------------------------------------
// MultiHeadAttention: out = proj(attn(qkv_proj(query)))
// B=4 S=2048 E=1024 H=16 HD=64.  scale = 1/sqrt(E) = 1/32.
// Pipeline: cvt(fp32->bf16) -> GEMM1(bias, bf16 out) -> flash-attn -> GEMM2(bias, f32 out)
// ---------------------------------------------------------------------------

typedef __bf16 bf16;
typedef __bf16 bf16x8 __attribute__((ext_vector_type(8)));
typedef __bf16 bf16x4 __attribute__((ext_vector_type(4)));
typedef float  f32x4  __attribute__((ext_vector_type(4)));

#define MFMA16(a, b, c) __builtin_amdgcn_mfma_f32_16x16x32_bf16((a), (b), (c), 0, 0, 0)

__device__ __forceinline__ void gload16(const void* g, void* l) {
  __builtin_amdgcn_global_load_lds(
      (const __attribute__((address_space(1))) void*)g,
      (__attribute__((address_space(3))) void*)l, 16, 0, 0);
}

// ---------------------------------------------------------------- convert ---
__global__ __launch_bounds__(256) void cvt_f32_bf16(const float* __restrict__ in,
                                                    bf16* __restrict__ out, int n4) {
  int i = blockIdx.x * 256 + threadIdx.x;
  if (i >= n4) return;
  const float4 v = ((const float4*)in)[i];
  bf16x4 o;
  o[0] = (bf16)v.x; o[1] = (bf16)v.y; o[2] = (bf16)v.z; o[3] = (bf16)v.w;
  ((bf16x4*)out)[i] = o;
}

// ------------------------------------------------------------------- GEMM ---
// C[M][N] = A[M][K] @ Bt[N][K]^T + bias[N].  m97 structure: 128x128 tile,
// BK=32, 4 waves (2x2), each wave 64x64 = 4x4 frags of 16x16x32 MFMA.
template <typename OutT>
__global__ __launch_bounds__(256, 2) void gemm_bt(const bf16* __restrict__ A,
                                                  const bf16* __restrict__ Bt,
                                                  const float* __restrict__ bias,
                                                  OutT* __restrict__ C,
                                                  int M, int N, int K) {
  __shared__ bf16 As[128 * 32];
  __shared__ bf16 Bs[128 * 32];
  const int tid = threadIdx.x;
  const int lane = tid & 63, wid = tid >> 6;
  const int l15 = lane & 15, lg = lane >> 4;
  const int wr = wid >> 1, wc = wid & 1;
  const int row0 = blockIdx.y * 128, col0 = blockIdx.x * 128;

  f32x4 acc[4][4];
#pragma unroll
  for (int m = 0; m < 4; ++m)
#pragma unroll
    for (int n = 0; n < 4; ++n) acc[m][n] = (f32x4){0.f, 0.f, 0.f, 0.f};

  for (int k0 = 0; k0 < K; k0 += 32) {
    __syncthreads();  // previous iter's LDS reads done
#pragma unroll
    for (int j = 0; j < 2; ++j) {
      const int c = j * 256 + tid;          // 16B chunk id, lane-ordered per wave
      const int r = c >> 2, cb = (c & 3) << 4;
      gload16((const char*)(A + (size_t)(row0 + r) * K + k0) + cb, (char*)As + c * 16);
      gload16((const char*)(Bt + (size_t)(col0 + r) * K + k0) + cb, (char*)Bs + c * 16);
    }
    __syncthreads();  // staging done (drains vmcnt)

    bf16x8 af[4], bfr[4];
#pragma unroll
    for (int m = 0; m < 4; ++m)
      af[m] = *(const bf16x8*)(As + ((wr * 64 + m * 16 + l15) << 5) + lg * 8);
#pragma unroll
    for (int n = 0; n < 4; ++n)
      bfr[n] = *(const bf16x8*)(Bs + ((wc * 64 + n * 16 + l15) << 5) + lg * 8);
#pragma unroll
    for (int m = 0; m < 4; ++m)
#pragma unroll
      for (int n = 0; n < 4; ++n) acc[m][n] = MFMA16(af[m], bfr[n], acc[m][n]);
  }

  // epilogue: C/D layout row=(lane>>4)*4+reg, col=lane&15
#pragma unroll
  for (int m = 0; m < 4; ++m) {
    const int grow0 = row0 + wr * 64 + m * 16 + lg * 4;
#pragma unroll
    for (int n = 0; n < 4; ++n) {
      const int gcol = col0 + wc * 64 + n * 16 + l15;
      const float bv = bias[gcol];
#pragma unroll
      for (int i = 0; i < 4; ++i)
        C[(size_t)(grow0 + i) * N + gcol] = (OutT)(acc[m][n][i] + bv);
    }
  }
}

// -------------------------------------------------------------- attention ---
// grid (S/64, H, B); block 256 = 4 waves, each wave owns 16 q-rows.
// qkv layout [B,S,3E]: q at col h*64, k at 1024+h*64, v at 2048+h*64.
// KV tiles of 64 keys staged in LDS; XOR-swizzle ^((row&7)<<4) kills the
// 128B-row 16-way bank conflict (G4).  Online softmax, fp32 state.
__global__ __launch_bounds__(256, 2) void attn_fwd(const bf16* __restrict__ qkv,
                                                   bf16* __restrict__ aout) {
  __shared__ bf16 Ks[64 * 64];      // [key][d], swizzled
  __shared__ bf16 Vt[64 * 64];      // [d][key], swizzled
  __shared__ bf16 Ps[4][16 * 64];   // per-wave P [qrow][key], swizzled

  const int qblk = blockIdx.x, h = blockIdx.y, b = blockIdx.z;
  const int tid = threadIdx.x, wid = tid >> 6, lane = tid & 63;
  const int l15 = lane & 15, lg = lane >> 4;
  const size_t sstride = 3072;
  const bf16* qbase = qkv + (size_t)b * 2048 * sstride;

  // Q fragments: A-frag row = lane&15, k = (lane>>4)*8 (+f*32)
  const int qrow = qblk * 64 + wid * 16 + l15;
  bf16x8 qf[2];
#pragma unroll
  for (int f = 0; f < 2; ++f)
    qf[f] = *(const bf16x8*)(qbase + (size_t)qrow * sstride + h * 64 + f * 32 + lg * 8);

  f32x4 o[4];
#pragma unroll
  for (int t = 0; t < 4; ++t) o[t] = (f32x4){0.f, 0.f, 0.f, 0.f};
  float mrow[4] = {-INFINITY, -INFINITY, -INFINITY, -INFINITY};
  float lrow[4] = {0.f, 0.f, 0.f, 0.f};

  for (int kt = 0; kt < 32; ++kt) {
    __syncthreads();  // previous tile's LDS reads done
    // stage K tile (64x64, reg->swizzled LDS) and V tile transposed
#pragma unroll
    for (int j = 0; j < 2; ++j) {
      const int c = j * 256 + tid;
      const int key = c >> 3;
      {  // K: 16B chunk (c&7)
        const int db = (c & 7) << 4;
        bf16x8 v = *(const bf16x8*)((const char*)(qbase + (size_t)(kt * 64 + key) * sstride + 1024 + h * 64) + db);
        *(bf16x8*)((char*)Ks + ((key * 128 + db) ^ ((key & 7) << 4))) = v;
      }
      {  // V: load 8 contiguous d, scatter-transpose into Vt[d][key]
        const int d0 = (c & 7) << 3;
        bf16x8 v = *(const bf16x8*)(qbase + (size_t)(kt * 64 + key) * sstride + 2048 + h * 64 + d0);
#pragma unroll
        for (int e = 0; e < 8; ++e) {
          const int d = d0 + e;
          *(bf16*)((char*)Vt + ((d * 128 + key * 2) ^ ((d & 7) << 4))) = v[e];
        }
      }
    }
    __syncthreads();  // staging done

    // ---- S = Q K^T / 32 : 4 col-tiles of 16 keys, K=64 in 2 mfma ----
    f32x4 s[4];
#pragma unroll
    for (int t = 0; t < 4; ++t) {
      s[t] = (f32x4){0.f, 0.f, 0.f, 0.f};
      const int key = t * 16 + l15;
#pragma unroll
      for (int kk = 0; kk < 2; ++kk) {
        bf16x8 kf = *(const bf16x8*)((const char*)Ks + ((key * 128 + kk * 64 + lg * 16) ^ ((key & 7) << 4)));
        s[t] = MFMA16(qf[kk], kf, s[t]);
      }
    }
#pragma unroll
    for (int t = 0; t < 4; ++t)
#pragma unroll
      for (int i = 0; i < 4; ++i) s[t][i] *= 0.03125f;  // 1/sqrt(1024)

    // ---- online softmax: rows lg*4+i live in the 16 lanes of group lg ----
    float mt[4], alpha[4];
#pragma unroll
    for (int i = 0; i < 4; ++i) {
      float v = fmaxf(fmaxf(s[0][i], s[1][i]), fmaxf(s[2][i], s[3][i]));
      v = fmaxf(v, __shfl_xor(v, 1));
      v = fmaxf(v, __shfl_xor(v, 2));
      v = fmaxf(v, __shfl_xor(v, 4));
      v = fmaxf(v, __shfl_xor(v, 8));
      const float mnew = fmaxf(mrow[i], v);
      alpha[i] = expf(mrow[i] - mnew);
      mrow[i] = mnew;
      mt[i] = mnew;
    }
    float psum[4] = {0.f, 0.f, 0.f, 0.f};
#pragma unroll
    for (int t = 0; t < 4; ++t)
#pragma unroll
      for (int i = 0; i < 4; ++i) {
        const float p = expf(s[t][i] - mt[i]);
        psum[i] += p;
        const int prow = lg * 4 + i, pcol = t * 16 + l15;
        *(bf16*)((char*)&Ps[wid][0] + ((prow * 128 + pcol * 2) ^ ((prow & 7) << 4))) = (bf16)p;
      }
#pragma unroll
    for (int i = 0; i < 4; ++i) {
      float v = psum[i];
      v += __shfl_xor(v, 1);
      v += __shfl_xor(v, 2);
      v += __shfl_xor(v, 4);
      v += __shfl_xor(v, 8);
      lrow[i] = alpha[i] * lrow[i] + v;
    }
#pragma unroll
    for (int t = 0; t < 4; ++t)
#pragma unroll
      for (int i = 0; i < 4; ++i) o[t][i] *= alpha[i];

    // ---- O += P V : P A-frags from own-wave LDS (in-order, no barrier) ----
#pragma unroll
    for (int kk = 0; kk < 2; ++kk) {
      bf16x8 pf = *(const bf16x8*)((const char*)&Ps[wid][0] + ((l15 * 128 + kk * 64 + lg * 16) ^ ((l15 & 7) << 4)));
#pragma unroll
      for (int t = 0; t < 4; ++t) {
        const int d = t * 16 + l15;
        bf16x8 vf = *(const bf16x8*)((const char*)Vt + ((d * 128 + kk * 64 + lg * 16) ^ ((d & 7) << 4)));
        o[t] = MFMA16(pf, vf, o[t]);
      }
    }
  }

  // epilogue: aout[b][row][h*64+d] = O/l
  bf16* ob = aout + ((size_t)b * 2048 + qblk * 64 + wid * 16) * 1024 + h * 64;
#pragma unroll
  for (int i = 0; i < 4; ++i) {
    const float inv = 1.0f / lrow[i];
    const int row = lg * 4 + i;
#pragma unroll
    for (int t = 0; t < 4; ++t)
      ob[(size_t)row * 1024 + t * 16 + l15] = (bf16)(o[t][i] * inv);
  }
}

// ------------------------------------------------------------------ launch ---
extern "C" void kernel_launch(void* const* d_in, const int* in_sizes, int n_in,
                              void* d_out, int out_size, void* d_ws, size_t ws_size,
                              hipStream_t stream) {
  const float* query = (const float*)d_in[0];
  // d_in[1] (key) and d_in[2] (value) are ignored by the reference module.
  const float* Wqkv = (const float*)d_in[3];
  const float* bqkv = (const float*)d_in[4];
  const float* Wout = (const float*)d_in[5];
  const float* bout = (const float*)d_in[6];
  float* out = (float*)d_out;

  constexpr int M = 8192;        // B*S
  constexpr int E = 1024, E3 = 3072;

  bf16* q_bf    = (bf16*)d_ws;                       //  8192*1024
  bf16* wqkv_bf = q_bf + (size_t)M * E;              //  3072*1024
  bf16* wout_bf = wqkv_bf + (size_t)E3 * E;          //  1024*1024
  bf16* qkv_bf  = wout_bf + (size_t)E * E;           //  8192*3072
  bf16* aout_bf = qkv_bf + (size_t)M * E3;           //  8192*1024   (total ~88 MB)

  cvt_f32_bf16<<<(M * E / 4 + 255) / 256, 256, 0, stream>>>(query, q_bf, M * E / 4);
  cvt_f32_bf16<<<(E3 * E / 4 + 255) / 256, 256, 0, stream>>>(Wqkv, wqkv_bf, E3 * E / 4);
  cvt_f32_bf16<<<(E * E / 4 + 255) / 256, 256, 0, stream>>>(Wout, wout_bf, E * E / 4);

  gemm_bt<bf16><<<dim3(E3 / 128, M / 128), 256, 0, stream>>>(q_bf, wqkv_bf, bqkv, qkv_bf, M, E3, E);
  attn_fwd<<<dim3(32, 16, 4), 256, 0, stream>>>(qkv_bf, aout_bf);
  gemm_bt<float><<<dim3(E / 128, M / 128), 256, 0, stream>>>(aout_bf, wout_bf, bout, out, M, E, E);
}